// Round 9
// baseline (723.678 us; speedup 1.0000x reference)
//
#include <hip/hip_runtime.h>

typedef unsigned int uint;
typedef unsigned short ushort;
typedef __attribute__((ext_vector_type(4))) float f32x4;
typedef __attribute__((ext_vector_type(8))) _Float16 f16x8;
typedef __attribute__((ext_vector_type(2))) _Float16 f16x2;

#define HQ 512
#define BN_EPS 1e-5f

// ---------------- fp16 <-> fp32 helpers ----------------
__device__ __forceinline__ ushort f2h(float f) {
  union { ushort s; _Float16 h; } u; u.h = (_Float16)f; return u.s;
}
__device__ __forceinline__ float h2f(ushort s) {
  union { ushort s; _Float16 h; } u; u.s = s; return (float)u.h;
}
__device__ __forceinline__ void unpack2(uint v, float& a, float& b) {
  union { uint u; _Float16 h[2]; } x; x.u = v; a = (float)x.h[0]; b = (float)x.h[1];
}
__device__ __forceinline__ uint pack2(float a, float b) {
  union { uint u; _Float16 h[2]; } x; x.h[0] = (_Float16)a; x.h[1] = (_Float16)b; return x.u;
}
// split fp32 v into hi (fp16) and lo (fp16 of residual); v ≈ hi + lo with ~2^-22 rel err
__device__ __forceinline__ void split2(float a, float b, uint& hi, uint& lo) {
  float ah = h2f(f2h(a)), bh = h2f(f2h(b));
  hi = pack2(ah, bh);
  lo = pack2(a - ah, b - bh);
}
// pack one value's hi/lo fp16 into a single uint (hi in low 16, lo in high 16)
__device__ __forceinline__ uint packhl(float v) {
  ushort hi = f2h(v);
  ushort lo = f2h(v - h2f(hi));
  return (uint)hi | ((uint)lo << 16);
}
// acc += hi + lo of a packed element, one VALU op (v_dot2_f32_f16)
__device__ __forceinline__ float addhl(uint v, float acc) {
  union { uint u; f16x2 h; } x; x.u = v;
#if __has_builtin(__builtin_amdgcn_fdot2)
  const f16x2 one = {(_Float16)1.0f, (_Float16)1.0f};
  return __builtin_amdgcn_fdot2(x.h, one, acc, false);
#else
  return acc + (float)x.h[0] + (float)x.h[1];
#endif
}

// ---------------- edge-index width detection ----------------
__global__ void detect_idx_kernel(const int* __restrict__ idx, int twoE, int* flag) {
  __shared__ int ok;
  if (threadIdx.x == 0) ok = 1;
  __syncthreads();
  for (int i = threadIdx.x; i < 2048; i += blockDim.x) {
    int p = 2 * i + 1;
    if (p < twoE && idx[p] != 0) ok = 0;
  }
  __syncthreads();
  if (threadIdx.x == 0) flag[0] = ok;   // 1 => int64 storage, 0 => int32
}

__device__ __forceinline__ int edge_at(const int* __restrict__ idx, int pos, int is64) {
  return is64 ? idx[2 * pos] : idx[pos];
}

// ---------------- CSR build ----------------
__global__ void degree_kernel(const int* __restrict__ idx, int E, const int* __restrict__ flag,
                              int* __restrict__ row_start) {
  int e = blockIdx.x * blockDim.x + threadIdx.x;
  if (e >= E) return;
  int is64 = flag[0];
  int d = edge_at(idx, E + e, is64);
  atomicAdd(&row_start[d + 1], 1);
}

__global__ void scan_kernel(int* __restrict__ data, int n) {  // inclusive scan over n+1 entries
  __shared__ int sh[1024];
  __shared__ int carry;
  if (threadIdx.x == 0) carry = 0;
  __syncthreads();
  for (int base = 0; base < n + 1; base += 1024) {
    int i = base + threadIdx.x;
    int v = (i < n + 1) ? data[i] : 0;
    sh[threadIdx.x] = v;
    __syncthreads();
    for (int off = 1; off < 1024; off <<= 1) {
      int t = (threadIdx.x >= (unsigned)off) ? sh[threadIdx.x - off] : 0;
      __syncthreads();
      sh[threadIdx.x] += t;
      __syncthreads();
    }
    int inc = sh[threadIdx.x] + carry;
    if (i < n + 1) data[i] = inc;
    __syncthreads();
    if (threadIdx.x == 0) carry += sh[1023];
    __syncthreads();
  }
}

__global__ void scatter_kernel(const int* __restrict__ idx, int E, const int* __restrict__ flag,
                               const int* __restrict__ row_start, int* __restrict__ cursor,
                               int* __restrict__ csr) {
  int e = blockIdx.x * blockDim.x + threadIdx.x;
  if (e >= E) return;
  int is64 = flag[0];
  int s = edge_at(idx, e, is64);
  int d = edge_at(idx, E + e, is64);
  int pos = atomicAdd(&cursor[d], 1);
  csr[row_start[d] + pos] = s;
}

// ---------------- weight / input prep (fp32 -> fp16 hi/lo) ----------------
__global__ void prep_weights_kernel(const float* __restrict__ lin0_w, const float* __restrict__ w1,
                                    const float* __restrict__ w2, ushort* __restrict__ wH,
                                    ushort* __restrict__ wL, int totalw) {
  int i4 = (blockIdx.x * blockDim.x + threadIdx.x) * 4;
  if (i4 >= totalw) return;
  const int W = HQ * HQ;
  const float* src; int off;
  if (i4 < W)          { src = lin0_w; off = i4; }
  else if (i4 < 4 * W) { src = w1;     off = i4 - W; }
  else                 { src = w2;     off = i4 - 4 * W; }
  float4 v = *(const float4*)(src + off);
  uint2 ph, pl;
  split2(v.x, v.y, ph.x, pl.x);
  split2(v.z, v.w, ph.y, pl.y);
  *(uint2*)(wH + i4) = ph;
  *(uint2*)(wL + i4) = pl;
}

__global__ void prep_x_kernel(const float* __restrict__ x, ushort* __restrict__ xH,
                              ushort* __restrict__ xL, float* __restrict__ out0, int N, int MP) {
  int i4 = (blockIdx.x * blockDim.x + threadIdx.x) * 4;
  if (i4 >= MP * HQ) return;
  int row = i4 >> 9;
  uint2 ph, pl;
  if (row < N) {
    float4 v = *(const float4*)(x + i4);
    *(float4*)(out0 + i4) = v;                       // embs[0] = x (exact fp32 copy)
    split2(v.x, v.y, ph.x, pl.x);
    split2(v.z, v.w, ph.y, pl.y);
  } else {
    ph.x = ph.y = pl.x = pl.y = 0u;                  // zero pad rows
  }
  *(uint2*)(xH + i4) = ph;
  *(uint2*)(xL + i4) = pl;
}

// ---------------- GIN aggregation: z[n] = h[n] + sum_{j->n} h[j] ----------------
// h packed (hi|lo<<16). XCD-pinned column slice (slice = blockIdx.x, fastest dim).
// Edges processed in chunks of 8 (independent loads) to break the latency chain.
__global__ void gather_slice_kernel(const uint* __restrict__ hp, ushort* __restrict__ zH,
                                    ushort* __restrict__ zL, const int* __restrict__ row_start,
                                    const int* __restrict__ csr, int N) {
  const int slice = blockIdx.x;                 // 0..7
  const int sub   = threadIdx.x >> 5;           // 0..7 (node sub-group)
  const int l     = threadIdx.x & 31;
  const int n = blockIdx.y * 8 + sub;
  if (n >= N) return;
  const int c0 = slice * 64 + l * 2;
  const uint* hc = hp + c0;
  uint2 v = *(const uint2*)(hc + (size_t)n * HQ);
  float a0 = addhl(v.x, 0.f), a1 = addhl(v.y, 0.f);
  const int s = row_start[n], e = row_start[n + 1];
  for (int j = s; j < e; j += 8) {
    int  cc[8];
    bool ok[8];
#pragma unroll
    for (int k = 0; k < 8; ++k) {
      const int jj = j + k;
      ok[k] = jj < e;
      cc[k] = csr[ok[k] ? jj : s];
    }
    uint2 w[8];
#pragma unroll
    for (int k = 0; k < 8; ++k) w[k] = *(const uint2*)(hc + (size_t)cc[k] * HQ);
#pragma unroll
    for (int k = 0; k < 8; ++k) {
      const float t0 = addhl(w[k].x, a0);
      const float t1 = addhl(w[k].y, a1);
      a0 = ok[k] ? t0 : a0;
      a1 = ok[k] ? t1 : a1;
    }
  }
  ushort h0 = f2h(a0), h1 = f2h(a1);
  uint zh = (uint)h0 | ((uint)h1 << 16);
  uint zl = (uint)f2h(a0 - h2f(h0)) | ((uint)f2h(a1 - h2f(h1)) << 16);
  __builtin_nontemporal_store(zh, (uint*)(zH + (size_t)n * HQ + c0));
  __builtin_nontemporal_store(zl, (uint*)(zL + (size_t)n * HQ + c0));
}

// ---------------- GEMM: C[m,n] = A[m,:] . W[n,:] + bias[n], optional ReLU ----------------
// 3-product double-fp16 (verified accurate): C ≈ AH·WH + AL·WH + AH·WL, fp32 acc.
// REGISTER-DIRECT: no LDS staging, no K-loop barriers. MFMA fragments are loaded
// straight from global (L2-resident by XCD-chunked swizzle: per-XCD A chunk 2.6MB +
// whole W 1MB < 4MB L2). Fragment pattern = row-major 16B/lane, 64B/row contiguous,
// L1 dedupes the 2x wave overlap. K fully unrolled -> offsets fold into immediates.
// 128x64 tile (BMxBN), 4 waves (2x2 of 64x32), mfma_f32_16x16x32_f16.
// STATS=1: per-column sum/sumsq (rows < Nvalid) -> LDS reduce -> one atomic/col/block.
// PACK=1: write packed hi|lo<<16 uints to CP instead of CH/CL planes.
template <int RELU, int STATS, int PACK>
__launch_bounds__(256)
__global__ void gemm3_kernel(const ushort* __restrict__ AH, const ushort* __restrict__ AL,
                             const ushort* __restrict__ WH, const ushort* __restrict__ WL,
                             const float* __restrict__ bias,
                             ushort* __restrict__ CH, ushort* __restrict__ CL,
                             uint* __restrict__ CP,
                             float* __restrict__ sums, int Nvalid, int MTm) {
  __shared__ float ssum[64];
  __shared__ float ssq[64];
  const int tid  = threadIdx.x;
  const int lane = tid & 63;
  const int wave = tid >> 6;

  // XCD-chunked swizzle (MTm divisible by 8; 8 n-tiles fastest within chunk)
  const int bid    = blockIdx.x;
  const int xcd    = bid & 7;
  const int local  = bid >> 3;
  const int chunk  = MTm >> 3;                 // m-tiles per XCD
  const int m_tile = xcd * chunk + (local >> 3);
  const int n_tile = local & 7;
  const int m0 = m_tile * 128;
  const int n0 = n_tile * 64;
  const int wm = (wave >> 1) * 64;             // wave row-half of the 128
  const int wn = (wave & 1) * 32;              // wave col-half of the 64

  if (STATS && tid < 64) { ssum[tid] = 0.f; ssq[tid] = 0.f; }

  f32x4 acc[4][2];
#pragma unroll
  for (int i = 0; i < 4; ++i)
#pragma unroll
    for (int j = 0; j < 2; ++j) acc[i][j] = (f32x4){0.f, 0.f, 0.f, 0.f};

  const int fr = lane & 15;
  const int kb = lane >> 4;

  // per-lane fragment row base pointers (k-offset = kt folds into imm offsets)
  const ushort* pAH[4];
  const ushort* pAL[4];
  const ushort* pWH[2];
  const ushort* pWL[2];
#pragma unroll
  for (int i = 0; i < 4; ++i) {
    const size_t ro = (size_t)(m0 + wm + i * 16 + fr) * HQ + kb * 8;
    pAH[i] = AH + ro;
    pAL[i] = AL + ro;
  }
#pragma unroll
  for (int j = 0; j < 2; ++j) {
    const size_t ro = (size_t)(n0 + wn + j * 16 + fr) * HQ + kb * 8;
    pWH[j] = WH + ro;
    pWL[j] = WL + ro;
  }

#pragma unroll
  for (int kt = 0; kt < HQ; kt += 32) {
    f16x8 afH[4], afL[4], bfH[2], bfL[2];
#pragma unroll
    for (int i = 0; i < 4; ++i) {
      afH[i] = *(const f16x8*)(pAH[i] + kt);
      afL[i] = *(const f16x8*)(pAL[i] + kt);
    }
#pragma unroll
    for (int j = 0; j < 2; ++j) {
      bfH[j] = *(const f16x8*)(pWH[j] + kt);
      bfL[j] = *(const f16x8*)(pWL[j] + kt);
    }
#pragma unroll
    for (int i = 0; i < 4; ++i)
#pragma unroll
      for (int j = 0; j < 2; ++j)
        acc[i][j] = __builtin_amdgcn_mfma_f32_16x16x32_f16(afH[i], bfH[j], acc[i][j], 0, 0, 0);
#pragma unroll
    for (int i = 0; i < 4; ++i)
#pragma unroll
      for (int j = 0; j < 2; ++j)
        acc[i][j] = __builtin_amdgcn_mfma_f32_16x16x32_f16(afL[i], bfH[j], acc[i][j], 0, 0, 0);
#pragma unroll
    for (int i = 0; i < 4; ++i)
#pragma unroll
      for (int j = 0; j < 2; ++j)
        acc[i][j] = __builtin_amdgcn_mfma_f32_16x16x32_f16(afH[i], bfL[j], acc[i][j], 0, 0, 0);
  }

  // epilogue: D col = lane&15, row = (lane>>4)*4 + r   [guide §3, m89/m91-verified]
#pragma unroll
  for (int j = 0; j < 2; ++j) {
    const int col = n0 + wn + j * 16 + fr;
    const float b = bias[col];
    float cs = 0.f, cq = 0.f;
#pragma unroll
    for (int i = 0; i < 4; ++i) {
      const int mb = m0 + wm + i * 16 + kb * 4;
#pragma unroll
      for (int r = 0; r < 4; ++r) {
        float v = acc[i][j][r] + b;
        if (RELU) v = fmaxf(v, 0.f);
        if (STATS) {
          const float vm = (mb + r < Nvalid) ? v : 0.f;
          cs += vm;
          cq += vm * vm;
        }
        const size_t oidx = (size_t)(mb + r) * HQ + col;
        if (PACK) {
          CP[oidx] = packhl(v);
        } else {
          ushort hi = f2h(v);
          CH[oidx] = hi;
          CL[oidx] = f2h(v - h2f(hi));
        }
      }
    }
    if (STATS) {
      // reduce across the 4 kb lanes (same fr/col): lane ids differ in bits 4,5
      cs += __shfl_xor(cs, 16); cq += __shfl_xor(cq, 16);
      cs += __shfl_xor(cs, 32); cq += __shfl_xor(cq, 32);
      if (kb == 0) {
        atomicAdd(&ssum[wn + j * 16 + fr], cs);
        atomicAdd(&ssq[wn + j * 16 + fr], cq);
      }
    }
  }
  if (STATS) {
    __syncthreads();
    if (tid < 64) {
      atomicAdd(&sums[n0 + tid], ssum[tid]);
      atomicAdd(&sums[HQ + n0 + tid], ssq[tid]);
    }
  }
}

// ---------------- BatchNorm finalize / apply ----------------
__global__ void bn_finalize_kernel(const float* __restrict__ sums, const float* __restrict__ gamma,
                                   const float* __restrict__ beta, float* __restrict__ scale,
                                   float* __restrict__ shift, int N) {
  int c = threadIdx.x;
  if (c < HQ) {
    float inv_n = 1.f / (float)N;
    float mu = sums[c] * inv_n;
    float var = fmaxf(sums[HQ + c] * inv_n - mu * mu, 0.f);
    float sc = gamma[c] * rsqrtf(var + BN_EPS);
    scale[c] = sc;
    shift[c] = beta[c] - mu * sc;
  }
}

__global__ void bn_apply_tanh_kernel(const ushort* __restrict__ zH, const ushort* __restrict__ zL,
                                     const float* __restrict__ scale, const float* __restrict__ shift,
                                     float* __restrict__ outp, uint* __restrict__ hp, int total) {
  int i8 = (blockIdx.x * blockDim.x + threadIdx.x) * 8;
  if (i8 >= total) return;
  int c0 = i8 & (HQ - 1);
  uint4 vh = *(const uint4*)(zH + i8);
  uint4 vl = *(const uint4*)(zL + i8);
  float a[8];
  {
    float t0, t1, u0, u1;
    unpack2(vh.x, t0, t1); unpack2(vl.x, u0, u1); a[0] = t0 + u0; a[1] = t1 + u1;
    unpack2(vh.y, t0, t1); unpack2(vl.y, u0, u1); a[2] = t0 + u0; a[3] = t1 + u1;
    unpack2(vh.z, t0, t1); unpack2(vl.z, u0, u1); a[4] = t0 + u0; a[5] = t1 + u1;
    unpack2(vh.w, t0, t1); unpack2(vl.w, u0, u1); a[6] = t0 + u0; a[7] = t1 + u1;
  }
  float4 sA = *(const float4*)(scale + c0);
  float4 sB = *(const float4*)(scale + c0 + 4);
  float4 hA = *(const float4*)(shift + c0);
  float4 hB = *(const float4*)(shift + c0 + 4);
  float y[8];
  y[0] = tanhf(fmaf(a[0], sA.x, hA.x));
  y[1] = tanhf(fmaf(a[1], sA.y, hA.y));
  y[2] = tanhf(fmaf(a[2], sA.z, hA.z));
  y[3] = tanhf(fmaf(a[3], sA.w, hA.w));
  y[4] = tanhf(fmaf(a[4], sB.x, hB.x));
  y[5] = tanhf(fmaf(a[5], sB.y, hB.y));
  y[6] = tanhf(fmaf(a[6], sB.z, hB.z));
  y[7] = tanhf(fmaf(a[7], sB.w, hB.w));
  *(float4*)(outp + i8)     = make_float4(y[0], y[1], y[2], y[3]);
  *(float4*)(outp + i8 + 4) = make_float4(y[4], y[5], y[6], y[7]);
  uint4 p0, p1;
  p0.x = packhl(y[0]); p0.y = packhl(y[1]); p0.z = packhl(y[2]); p0.w = packhl(y[3]);
  p1.x = packhl(y[4]); p1.y = packhl(y[5]); p1.z = packhl(y[6]); p1.w = packhl(y[7]);
  *(uint4*)(hp + i8)     = p0;
  *(uint4*)(hp + i8 + 4) = p1;
}

// ---------------- launcher ----------------
extern "C" void kernel_launch(void* const* d_in, const int* in_sizes, int n_in,
                              void* d_out, int out_size, void* d_ws, size_t ws_size,
                              hipStream_t stream) {
  const float* x      = (const float*)d_in[0];
  const int*   idx    = (const int*)  d_in[1];
  const float* lin0_w = (const float*)d_in[2];
  const float* lin0_b = (const float*)d_in[3];
  const float* w1     = (const float*)d_in[4];
  const float* b1     = (const float*)d_in[5];
  const float* w2     = (const float*)d_in[6];
  const float* b2     = (const float*)d_in[7];
  const float* gamma  = (const float*)d_in[8];
  const float* beta   = (const float*)d_in[9];
  float* out = (float*)d_out;

  const int N    = in_sizes[0] / HQ;           // 10000
  const int twoE = in_sizes[1];                // 2*E
  const int E    = twoE / 2;
  const int L    = in_sizes[4] / (HQ * HQ);    // 3
  // pad M so 128-row m-tiles divide into 8 XCD chunks: MP = 10240, MTm = 80
  const int MP   = ((N + 1023) / 1024) * 1024;
  const int MTm  = MP / 128;
  const size_t NH = (size_t)N * HQ;
  const size_t T  = (size_t)MP * HQ;           // padded tensor elems

  // workspace carve (all 16B-aligned)
  char* wsp = (char*)d_ws;
  int*    flag  = (int*)wsp;
  uint*   hbP   = (uint*)(wsp + 256);          // packed h (hi|lo<<16), T uints
  ushort* zAH   = (ushort*)(hbP + T);
  ushort* zAL   = zAH + T;
  ushort* zBH   = zAL + T;
  ushort* zBL   = zBH + T;
  ushort* wHp   = zBL + T;
  ushort* wLp   = wHp + (size_t)(1 + 2 * L) * HQ * HQ;
  int*    row_start = (int*)(wLp + (size_t)(1 + 2 * L) * HQ * HQ);
  int*    cursor    = row_start + (N + 1);
  int*    csr       = cursor + N;
  float*  bnsums    = (float*)(csr + E);       // 3 layers x 2*HQ
  float*  bnscale   = bnsums + 6 * HQ;
  float*  bnshift   = bnscale + HQ;

  hipMemsetAsync(row_start, 0, (size_t)(2 * N + 1) * sizeof(int), stream);
  hipMemsetAsync(bnsums, 0, 6 * HQ * sizeof(float), stream);
  detect_idx_kernel<<<1, 256, 0, stream>>>(idx, twoE, flag);

  const int totalw = (1 + 2 * L) * HQ * HQ;
  prep_weights_kernel<<<(totalw / 4 + 255) / 256, 256, 0, stream>>>(lin0_w, w1, w2, wHp, wLp, totalw);
  prep_x_kernel<<<((int)(T / 4) + 255) / 256, 256, 0, stream>>>(x, zAH, zAL, out, N, MP);

  degree_kernel<<<(E + 255) / 256, 256, 0, stream>>>(idx, E, flag, row_start);
  scan_kernel<<<1, 1024, 0, stream>>>(row_start, N);
  scatter_kernel<<<(E + 255) / 256, 256, 0, stream>>>(idx, E, flag, row_start, cursor, csr);

  const int ggrid = MTm * 8;                   // 640 blocks, 1D (XCD swizzle inside)

  // h0 = x @ lin0_w.T + lin0_b   (no activation), packed output
  gemm3_kernel<0, 0, 1><<<ggrid, 256, 0, stream>>>(
      zAH, zAL, wHp, wLp, lin0_b, nullptr, nullptr, hbP, nullptr, N, MTm);

  for (int l = 0; l < L; ++l) {
    gather_slice_kernel<<<dim3(HQ / 64, (N + 7) / 8), 256, 0, stream>>>(
        hbP, zAH, zAL, row_start, csr, N);
    gemm3_kernel<1, 0, 0><<<ggrid, 256, 0, stream>>>(
        zAH, zAL, wHp + (size_t)(1 + l) * HQ * HQ, wLp + (size_t)(1 + l) * HQ * HQ,
        b1 + (size_t)l * HQ, zBH, zBL, nullptr, nullptr, N, MTm);
    gemm3_kernel<1, 1, 0><<<ggrid, 256, 0, stream>>>(
        zBH, zBL, wHp + (size_t)(1 + L + l) * HQ * HQ, wLp + (size_t)(1 + L + l) * HQ * HQ,
        b2 + (size_t)l * HQ, zAH, zAL, nullptr, bnsums + 2 * HQ * l, N, MTm);
    bn_finalize_kernel<<<1, HQ, 0, stream>>>(bnsums + 2 * HQ * l, gamma + (size_t)l * HQ,
                                             beta + (size_t)l * HQ, bnscale, bnshift, N);
    bn_apply_tanh_kernel<<<((int)(NH / 8) + 255) / 256, 256, 0, stream>>>(
        zAH, zAL, bnscale, bnshift, out + (size_t)(l + 1) * NH, hbP, (int)NH);
  }
}

// Round 10
// 507.591 us; speedup vs baseline: 1.4257x; 1.4257x over previous
//
#include <hip/hip_runtime.h>

typedef unsigned int uint;
typedef unsigned short ushort;
typedef __attribute__((ext_vector_type(4))) float f32x4;
typedef __attribute__((ext_vector_type(8))) _Float16 f16x8;
typedef __attribute__((ext_vector_type(2))) _Float16 f16x2;

#define HQ 512
#define BN_EPS 1e-5f

// ---------------- fp16 <-> fp32 helpers ----------------
__device__ __forceinline__ ushort f2h(float f) {
  union { ushort s; _Float16 h; } u; u.h = (_Float16)f; return u.s;
}
__device__ __forceinline__ float h2f(ushort s) {
  union { ushort s; _Float16 h; } u; u.s = s; return (float)u.h;
}
__device__ __forceinline__ void unpack2(uint v, float& a, float& b) {
  union { uint u; _Float16 h[2]; } x; x.u = v; a = (float)x.h[0]; b = (float)x.h[1];
}
__device__ __forceinline__ uint pack2(float a, float b) {
  union { uint u; _Float16 h[2]; } x; x.h[0] = (_Float16)a; x.h[1] = (_Float16)b; return x.u;
}
// split fp32 v into hi (fp16) and lo (fp16 of residual); v ≈ hi + lo with ~2^-22 rel err
__device__ __forceinline__ void split2(float a, float b, uint& hi, uint& lo) {
  float ah = h2f(f2h(a)), bh = h2f(f2h(b));
  hi = pack2(ah, bh);
  lo = pack2(a - ah, b - bh);
}
// pack one value's hi/lo fp16 into a single uint (hi in low 16, lo in high 16)
__device__ __forceinline__ uint packhl(float v) {
  ushort hi = f2h(v);
  ushort lo = f2h(v - h2f(hi));
  return (uint)hi | ((uint)lo << 16);
}
// acc += hi + lo of a packed element, one VALU op (v_dot2_f32_f16)
__device__ __forceinline__ float addhl(uint v, float acc) {
  union { uint u; f16x2 h; } x; x.u = v;
#if __has_builtin(__builtin_amdgcn_fdot2)
  const f16x2 one = {(_Float16)1.0f, (_Float16)1.0f};
  return __builtin_amdgcn_fdot2(x.h, one, acc, false);
#else
  return acc + (float)x.h[0] + (float)x.h[1];
#endif
}

// ---------------- async global->LDS (16B/lane) ----------------
__device__ __forceinline__ void gload_lds16(const ushort* g, ushort* l) {
  __builtin_amdgcn_global_load_lds(
      (const __attribute__((address_space(1))) void*)(const void*)g,
      (__attribute__((address_space(3))) void*)(void*)l,
      16, 0, 0);
}

// ---------------- edge-index width detection ----------------
__global__ void detect_idx_kernel(const int* __restrict__ idx, int twoE, int* flag) {
  __shared__ int ok;
  if (threadIdx.x == 0) ok = 1;
  __syncthreads();
  for (int i = threadIdx.x; i < 2048; i += blockDim.x) {
    int p = 2 * i + 1;
    if (p < twoE && idx[p] != 0) ok = 0;
  }
  __syncthreads();
  if (threadIdx.x == 0) flag[0] = ok;   // 1 => int64 storage, 0 => int32
}

__device__ __forceinline__ int edge_at(const int* __restrict__ idx, int pos, int is64) {
  return is64 ? idx[2 * pos] : idx[pos];
}

// ---------------- CSR build ----------------
__global__ void degree_kernel(const int* __restrict__ idx, int E, const int* __restrict__ flag,
                              int* __restrict__ row_start) {
  int e = blockIdx.x * blockDim.x + threadIdx.x;
  if (e >= E) return;
  int is64 = flag[0];
  int d = edge_at(idx, E + e, is64);
  atomicAdd(&row_start[d + 1], 1);
}

__global__ void scan_kernel(int* __restrict__ data, int n) {  // inclusive scan over n+1 entries
  __shared__ int sh[1024];
  __shared__ int carry;
  if (threadIdx.x == 0) carry = 0;
  __syncthreads();
  for (int base = 0; base < n + 1; base += 1024) {
    int i = base + threadIdx.x;
    int v = (i < n + 1) ? data[i] : 0;
    sh[threadIdx.x] = v;
    __syncthreads();
    for (int off = 1; off < 1024; off <<= 1) {
      int t = (threadIdx.x >= (unsigned)off) ? sh[threadIdx.x - off] : 0;
      __syncthreads();
      sh[threadIdx.x] += t;
      __syncthreads();
    }
    int inc = sh[threadIdx.x] + carry;
    if (i < n + 1) data[i] = inc;
    __syncthreads();
    if (threadIdx.x == 0) carry += sh[1023];
    __syncthreads();
  }
}

__global__ void scatter_kernel(const int* __restrict__ idx, int E, const int* __restrict__ flag,
                               const int* __restrict__ row_start, int* __restrict__ cursor,
                               int* __restrict__ csr) {
  int e = blockIdx.x * blockDim.x + threadIdx.x;
  if (e >= E) return;
  int is64 = flag[0];
  int s = edge_at(idx, e, is64);
  int d = edge_at(idx, E + e, is64);
  int pos = atomicAdd(&cursor[d], 1);
  csr[row_start[d] + pos] = s;
}

// ---------------- weight / input prep (fp32 -> fp16 hi/lo) ----------------
__global__ void prep_weights_kernel(const float* __restrict__ lin0_w, const float* __restrict__ w1,
                                    const float* __restrict__ w2, ushort* __restrict__ wH,
                                    ushort* __restrict__ wL, int totalw) {
  int i4 = (blockIdx.x * blockDim.x + threadIdx.x) * 4;
  if (i4 >= totalw) return;
  const int W = HQ * HQ;
  const float* src; int off;
  if (i4 < W)          { src = lin0_w; off = i4; }
  else if (i4 < 4 * W) { src = w1;     off = i4 - W; }
  else                 { src = w2;     off = i4 - 4 * W; }
  float4 v = *(const float4*)(src + off);
  uint2 ph, pl;
  split2(v.x, v.y, ph.x, pl.x);
  split2(v.z, v.w, ph.y, pl.y);
  *(uint2*)(wH + i4) = ph;
  *(uint2*)(wL + i4) = pl;
}

__global__ void prep_x_kernel(const float* __restrict__ x, ushort* __restrict__ xH,
                              ushort* __restrict__ xL, float* __restrict__ out0, int N, int MP) {
  int i4 = (blockIdx.x * blockDim.x + threadIdx.x) * 4;
  if (i4 >= MP * HQ) return;
  int row = i4 >> 9;
  uint2 ph, pl;
  if (row < N) {
    float4 v = *(const float4*)(x + i4);
    *(float4*)(out0 + i4) = v;                       // embs[0] = x (exact fp32 copy)
    split2(v.x, v.y, ph.x, pl.x);
    split2(v.z, v.w, ph.y, pl.y);
  } else {
    ph.x = ph.y = pl.x = pl.y = 0u;                  // zero pad rows
  }
  *(uint2*)(xH + i4) = ph;
  *(uint2*)(xL + i4) = pl;
}

// ---------------- GIN aggregation: z[n] = h[n] + sum_{j->n} h[j] ----------------
// h packed (hi|lo<<16). XCD-pinned column slice (slice = blockIdx.x, fastest dim).
// Edges processed in chunks of 8 (independent loads) to break the latency chain.
__global__ void gather_slice_kernel(const uint* __restrict__ hp, ushort* __restrict__ zH,
                                    ushort* __restrict__ zL, const int* __restrict__ row_start,
                                    const int* __restrict__ csr, int N) {
  const int slice = blockIdx.x;                 // 0..7
  const int sub   = threadIdx.x >> 5;           // 0..7 (node sub-group)
  const int l     = threadIdx.x & 31;
  const int n = blockIdx.y * 8 + sub;
  if (n >= N) return;
  const int c0 = slice * 64 + l * 2;
  const uint* hc = hp + c0;
  uint2 v = *(const uint2*)(hc + (size_t)n * HQ);
  float a0 = addhl(v.x, 0.f), a1 = addhl(v.y, 0.f);
  const int s = row_start[n], e = row_start[n + 1];
  for (int j = s; j < e; j += 8) {
    int  cc[8];
    bool ok[8];
#pragma unroll
    for (int k = 0; k < 8; ++k) {
      const int jj = j + k;
      ok[k] = jj < e;
      cc[k] = csr[ok[k] ? jj : s];
    }
    uint2 w[8];
#pragma unroll
    for (int k = 0; k < 8; ++k) w[k] = *(const uint2*)(hc + (size_t)cc[k] * HQ);
#pragma unroll
    for (int k = 0; k < 8; ++k) {
      const float t0 = addhl(w[k].x, a0);
      const float t1 = addhl(w[k].y, a1);
      a0 = ok[k] ? t0 : a0;
      a1 = ok[k] ? t1 : a1;
    }
  }
  ushort h0 = f2h(a0), h1 = f2h(a1);
  uint zh = (uint)h0 | ((uint)h1 << 16);
  uint zl = (uint)f2h(a0 - h2f(h0)) | ((uint)f2h(a1 - h2f(h1)) << 16);
  __builtin_nontemporal_store(zh, (uint*)(zH + (size_t)n * HQ + c0));
  __builtin_nontemporal_store(zl, (uint*)(zL + (size_t)n * HQ + c0));
}

// ---------------- GEMM: C[m,n] = A[m,:] . W[n,:] + bias[n], optional ReLU ----------------
// 3-product double-fp16 (accuracy-verified): C ≈ AH·WH + AL·WH + AH·WL, fp32 acc.
// 128x64 tile, BK=32, 4 waves (2x2 of 64x32), mfma_f32_16x16x32_f16, LDS staging.
// T4 counted-vmcnt pipeline, 3-buffer LDS rotation (72 KB, 2 blocks/CU):
//   per iter t: s_waitcnt vmcnt(6)   (drains stage t-2; leaves stage t-1 in flight)
//              s_barrier             (stage t-2 visible to all waves)
//              STAGE((t+2)%3)        (issued post-barrier: (t+2)%3==(t-1)%3 buffer is
//                                     provably drained by all waves at this point)
//              COMPUTE(t%3)
// Tail: redundant clamped stages keep the vmcnt count uniform (targets never re-read).
// STATS=1: per-column sum/sumsq (rows < Nvalid) -> LDS reduce -> one atomic/col/block.
// PACK=1: write packed hi|lo<<16 uints to CP instead of CH/CL planes.
template <int RELU, int STATS, int PACK>
__launch_bounds__(256)
__global__ void gemm3_kernel(const ushort* __restrict__ AH, const ushort* __restrict__ AL,
                             const ushort* __restrict__ WH, const ushort* __restrict__ WL,
                             const float* __restrict__ bias,
                             ushort* __restrict__ CH, ushort* __restrict__ CL,
                             uint* __restrict__ CP,
                             float* __restrict__ sums, int Nvalid, int MTm) {
  __shared__ ushort AsH[3][128 * 32];
  __shared__ ushort AsL[3][128 * 32];
  __shared__ ushort BsH[3][64 * 32];
  __shared__ ushort BsL[3][64 * 32];
  __shared__ float ssum[64];
  __shared__ float ssq[64];
  const int tid  = threadIdx.x;
  const int lane = tid & 63;
  const int wave = tid >> 6;

  // XCD-chunked swizzle (MTm divisible by 8; 8 n-tiles fastest within chunk)
  const int bid    = blockIdx.x;
  const int xcd    = bid & 7;
  const int local  = bid >> 3;
  const int chunk  = MTm >> 3;                 // m-tiles per XCD
  const int m_tile = xcd * chunk + (local >> 3);
  const int n_tile = local & 7;
  const int m0 = m_tile * 128;
  const int n0 = n_tile * 64;
  const int wm = (wave >> 1) * 64;             // wave row-half of the 128
  const int wn = (wave & 1) * 32;              // wave col-half of the 64

  if (STATS && tid < 64) { ssum[tid] = 0.f; ssq[tid] = 0.f; }

  f32x4 acc[4][2];
#pragma unroll
  for (int i = 0; i < 4; ++i)
#pragma unroll
    for (int j = 0; j < 2; ++j) acc[i][j] = (f32x4){0.f, 0.f, 0.f, 0.f};

  const int fr = lane & 15;
  const int kb = lane >> 4;
  const int srow = tid >> 2;          // staging: row = tid/4, col = (tid%4)*8
  const int scol = (tid & 3) * 8;

#define STAGE(buf, kt)                                                        \
  {                                                                           \
    const size_t ga0 = (size_t)(m0 + srow) * HQ + (kt) + scol;                \
    const size_t ga1 = ga0 + (size_t)64 * HQ;                                 \
    const size_t gb  = (size_t)(n0 + srow) * HQ + (kt) + scol;                \
    gload_lds16(AH + ga0, &AsH[buf][wave * 512]);                             \
    gload_lds16(AH + ga1, &AsH[buf][2048 + wave * 512]);                      \
    gload_lds16(AL + ga0, &AsL[buf][wave * 512]);                             \
    gload_lds16(AL + ga1, &AsL[buf][2048 + wave * 512]);                      \
    gload_lds16(WH + gb,  &BsH[buf][wave * 512]);                             \
    gload_lds16(WL + gb,  &BsL[buf][wave * 512]);                             \
  }

#define COMPUTE(buf)                                                          \
  {                                                                           \
    f16x8 afH[4], afL[4], bfH[2], bfL[2];                                     \
    _Pragma("unroll")                                                         \
    for (int i = 0; i < 4; ++i) {                                             \
      afH[i] = *(const f16x8*)&AsH[buf][(wm + i * 16 + fr) * 32 + kb * 8];    \
      afL[i] = *(const f16x8*)&AsL[buf][(wm + i * 16 + fr) * 32 + kb * 8];    \
    }                                                                         \
    _Pragma("unroll")                                                         \
    for (int j = 0; j < 2; ++j) {                                             \
      bfH[j] = *(const f16x8*)&BsH[buf][(wn + j * 16 + fr) * 32 + kb * 8];    \
      bfL[j] = *(const f16x8*)&BsL[buf][(wn + j * 16 + fr) * 32 + kb * 8];    \
    }                                                                         \
    _Pragma("unroll")                                                         \
    for (int i = 0; i < 4; ++i)                                               \
      _Pragma("unroll")                                                       \
      for (int j = 0; j < 2; ++j)                                             \
        acc[i][j] = __builtin_amdgcn_mfma_f32_16x16x32_f16(afH[i], bfH[j], acc[i][j], 0, 0, 0); \
    _Pragma("unroll")                                                         \
    for (int i = 0; i < 4; ++i)                                               \
      _Pragma("unroll")                                                       \
      for (int j = 0; j < 2; ++j)                                             \
        acc[i][j] = __builtin_amdgcn_mfma_f32_16x16x32_f16(afL[i], bfH[j], acc[i][j], 0, 0, 0); \
    _Pragma("unroll")                                                         \
    for (int i = 0; i < 4; ++i)                                               \
      _Pragma("unroll")                                                       \
      for (int j = 0; j < 2; ++j)                                             \
        acc[i][j] = __builtin_amdgcn_mfma_f32_16x16x32_f16(afH[i], bfL[j], acc[i][j], 0, 0, 0); \
  }

  STAGE(0, 0);
  STAGE(1, 32);
#pragma unroll
  for (int t = 0; t < 16; ++t) {
    asm volatile("s_waitcnt vmcnt(6)" ::: "memory");   // stage t-2 landed (t-1 stays in flight)
    __builtin_amdgcn_s_barrier();                      // all waves: buf t readable, buf (t-1)%3 drained
    __builtin_amdgcn_sched_barrier(0);
    asm volatile("" ::: "memory");
    const int sidx = (t + 2 < 16) ? (t + 2) : 15;      // clamped redundant tail stages
    STAGE((t + 2) % 3, sidx * 32);
    COMPUTE(t % 3);
  }
#undef STAGE
#undef COMPUTE

  // epilogue: D col = lane&15, row = (lane>>4)*4 + r   [guide §3, m89/m91-verified]
#pragma unroll
  for (int j = 0; j < 2; ++j) {
    const int col = n0 + wn + j * 16 + fr;
    const float b = bias[col];
    float cs = 0.f, cq = 0.f;
#pragma unroll
    for (int i = 0; i < 4; ++i) {
      const int mb = m0 + wm + i * 16 + kb * 4;
#pragma unroll
      for (int r = 0; r < 4; ++r) {
        float v = acc[i][j][r] + b;
        if (RELU) v = fmaxf(v, 0.f);
        if (STATS) {
          const float vm = (mb + r < Nvalid) ? v : 0.f;
          cs += vm;
          cq += vm * vm;
        }
        const size_t oidx = (size_t)(mb + r) * HQ + col;
        if (PACK) {
          CP[oidx] = packhl(v);
        } else {
          ushort hi = f2h(v);
          CH[oidx] = hi;
          CL[oidx] = f2h(v - h2f(hi));
        }
      }
    }
    if (STATS) {
      // reduce across the 4 kb lanes (same fr/col): lane ids differ in bits 4,5
      cs += __shfl_xor(cs, 16); cq += __shfl_xor(cq, 16);
      cs += __shfl_xor(cs, 32); cq += __shfl_xor(cq, 32);
      if (kb == 0) {
        atomicAdd(&ssum[wn + j * 16 + fr], cs);
        atomicAdd(&ssq[wn + j * 16 + fr], cq);
      }
    }
  }
  if (STATS) {
    __syncthreads();
    if (tid < 64) {
      atomicAdd(&sums[n0 + tid], ssum[tid]);
      atomicAdd(&sums[HQ + n0 + tid], ssq[tid]);
    }
  }
}

// ---------------- BatchNorm finalize / apply ----------------
__global__ void bn_finalize_kernel(const float* __restrict__ sums, const float* __restrict__ gamma,
                                   const float* __restrict__ beta, float* __restrict__ scale,
                                   float* __restrict__ shift, int N) {
  int c = threadIdx.x;
  if (c < HQ) {
    float inv_n = 1.f / (float)N;
    float mu = sums[c] * inv_n;
    float var = fmaxf(sums[HQ + c] * inv_n - mu * mu, 0.f);
    float sc = gamma[c] * rsqrtf(var + BN_EPS);
    scale[c] = sc;
    shift[c] = beta[c] - mu * sc;
  }
}

__global__ void bn_apply_tanh_kernel(const ushort* __restrict__ zH, const ushort* __restrict__ zL,
                                     const float* __restrict__ scale, const float* __restrict__ shift,
                                     float* __restrict__ outp, uint* __restrict__ hp, int total) {
  int i8 = (blockIdx.x * blockDim.x + threadIdx.x) * 8;
  if (i8 >= total) return;
  int c0 = i8 & (HQ - 1);
  uint4 vh = *(const uint4*)(zH + i8);
  uint4 vl = *(const uint4*)(zL + i8);
  float a[8];
  {
    float t0, t1, u0, u1;
    unpack2(vh.x, t0, t1); unpack2(vl.x, u0, u1); a[0] = t0 + u0; a[1] = t1 + u1;
    unpack2(vh.y, t0, t1); unpack2(vl.y, u0, u1); a[2] = t0 + u0; a[3] = t1 + u1;
    unpack2(vh.z, t0, t1); unpack2(vl.z, u0, u1); a[4] = t0 + u0; a[5] = t1 + u1;
    unpack2(vh.w, t0, t1); unpack2(vl.w, u0, u1); a[6] = t0 + u0; a[7] = t1 + u1;
  }
  float4 sA = *(const float4*)(scale + c0);
  float4 sB = *(const float4*)(scale + c0 + 4);
  float4 hA = *(const float4*)(shift + c0);
  float4 hB = *(const float4*)(shift + c0 + 4);
  float y[8];
  y[0] = tanhf(fmaf(a[0], sA.x, hA.x));
  y[1] = tanhf(fmaf(a[1], sA.y, hA.y));
  y[2] = tanhf(fmaf(a[2], sA.z, hA.z));
  y[3] = tanhf(fmaf(a[3], sA.w, hA.w));
  y[4] = tanhf(fmaf(a[4], sB.x, hB.x));
  y[5] = tanhf(fmaf(a[5], sB.y, hB.y));
  y[6] = tanhf(fmaf(a[6], sB.z, hB.z));
  y[7] = tanhf(fmaf(a[7], sB.w, hB.w));
  *(float4*)(outp + i8)     = make_float4(y[0], y[1], y[2], y[3]);
  *(float4*)(outp + i8 + 4) = make_float4(y[4], y[5], y[6], y[7]);
  uint4 p0, p1;
  p0.x = packhl(y[0]); p0.y = packhl(y[1]); p0.z = packhl(y[2]); p0.w = packhl(y[3]);
  p1.x = packhl(y[4]); p1.y = packhl(y[5]); p1.z = packhl(y[6]); p1.w = packhl(y[7]);
  *(uint4*)(hp + i8)     = p0;
  *(uint4*)(hp + i8 + 4) = p1;
}

// ---------------- launcher ----------------
extern "C" void kernel_launch(void* const* d_in, const int* in_sizes, int n_in,
                              void* d_out, int out_size, void* d_ws, size_t ws_size,
                              hipStream_t stream) {
  const float* x      = (const float*)d_in[0];
  const int*   idx    = (const int*)  d_in[1];
  const float* lin0_w = (const float*)d_in[2];
  const float* lin0_b = (const float*)d_in[3];
  const float* w1     = (const float*)d_in[4];
  const float* b1     = (const float*)d_in[5];
  const float* w2     = (const float*)d_in[6];
  const float* b2     = (const float*)d_in[7];
  const float* gamma  = (const float*)d_in[8];
  const float* beta   = (const float*)d_in[9];
  float* out = (float*)d_out;

  const int N    = in_sizes[0] / HQ;           // 10000
  const int twoE = in_sizes[1];                // 2*E
  const int E    = twoE / 2;
  const int L    = in_sizes[4] / (HQ * HQ);    // 3
  // pad M so 128-row m-tiles divide into 8 XCD chunks: MP = 10240, MTm = 80
  const int MP   = ((N + 1023) / 1024) * 1024;
  const int MTm  = MP / 128;
  const size_t NH = (size_t)N * HQ;
  const size_t T  = (size_t)MP * HQ;           // padded tensor elems

  // workspace carve (all 16B-aligned)
  char* wsp = (char*)d_ws;
  int*    flag  = (int*)wsp;
  uint*   hbP   = (uint*)(wsp + 256);          // packed h (hi|lo<<16), T uints
  ushort* zAH   = (ushort*)(hbP + T);
  ushort* zAL   = zAH + T;
  ushort* zBH   = zAL + T;
  ushort* zBL   = zBH + T;
  ushort* wHp   = zBL + T;
  ushort* wLp   = wHp + (size_t)(1 + 2 * L) * HQ * HQ;
  int*    row_start = (int*)(wLp + (size_t)(1 + 2 * L) * HQ * HQ);
  int*    cursor    = row_start + (N + 1);
  int*    csr       = cursor + N;
  float*  bnsums    = (float*)(csr + E);       // 3 layers x 2*HQ
  float*  bnscale   = bnsums + 6 * HQ;
  float*  bnshift   = bnscale + HQ;

  hipMemsetAsync(row_start, 0, (size_t)(2 * N + 1) * sizeof(int), stream);
  hipMemsetAsync(bnsums, 0, 6 * HQ * sizeof(float), stream);
  detect_idx_kernel<<<1, 256, 0, stream>>>(idx, twoE, flag);

  const int totalw = (1 + 2 * L) * HQ * HQ;
  prep_weights_kernel<<<(totalw / 4 + 255) / 256, 256, 0, stream>>>(lin0_w, w1, w2, wHp, wLp, totalw);
  prep_x_kernel<<<((int)(T / 4) + 255) / 256, 256, 0, stream>>>(x, zAH, zAL, out, N, MP);

  degree_kernel<<<(E + 255) / 256, 256, 0, stream>>>(idx, E, flag, row_start);
  scan_kernel<<<1, 1024, 0, stream>>>(row_start, N);
  scatter_kernel<<<(E + 255) / 256, 256, 0, stream>>>(idx, E, flag, row_start, cursor, csr);

  const int ggrid = MTm * 8;                   // 640 blocks, 1D (XCD swizzle inside)

  // h0 = x @ lin0_w.T + lin0_b   (no activation), packed output
  gemm3_kernel<0, 0, 1><<<ggrid, 256, 0, stream>>>(
      zAH, zAL, wHp, wLp, lin0_b, nullptr, nullptr, hbP, nullptr, N, MTm);

  for (int l = 0; l < L; ++l) {
    gather_slice_kernel<<<dim3(HQ / 64, (N + 7) / 8), 256, 0, stream>>>(
        hbP, zAH, zAL, row_start, csr, N);
    gemm3_kernel<1, 0, 0><<<ggrid, 256, 0, stream>>>(
        zAH, zAL, wHp + (size_t)(1 + l) * HQ * HQ, wLp + (size_t)(1 + l) * HQ * HQ,
        b1 + (size_t)l * HQ, zBH, zBL, nullptr, nullptr, N, MTm);
    gemm3_kernel<1, 1, 0><<<ggrid, 256, 0, stream>>>(
        zBH, zBL, wHp + (size_t)(1 + L + l) * HQ * HQ, wLp + (size_t)(1 + L + l) * HQ * HQ,
        b2 + (size_t)l * HQ, zAH, zAL, nullptr, bnsums + 2 * HQ * l, N, MTm);
    bn_finalize_kernel<<<1, HQ, 0, stream>>>(bnsums + 2 * HQ * l, gamma + (size_t)l * HQ,
                                             beta + (size_t)l * HQ, bnscale, bnshift, N);
    bn_apply_tanh_kernel<<<((int)(NH / 8) + 255) / 256, 256, 0, stream>>>(
        zAH, zAL, bnscale, bnshift, out + (size_t)(l + 1) * NH, hbP, (int)NH);
  }
}

// Round 11
// 454.761 us; speedup vs baseline: 1.5913x; 1.1162x over previous
//
#include <hip/hip_runtime.h>

typedef unsigned int uint;
typedef unsigned short ushort;
typedef __attribute__((ext_vector_type(4))) float f32x4;
typedef __attribute__((ext_vector_type(8))) _Float16 f16x8;
typedef __attribute__((ext_vector_type(2))) _Float16 f16x2;

#define HQ 512
#define BN_EPS 1e-5f

// ---------------- fp16 <-> fp32 helpers ----------------
__device__ __forceinline__ ushort f2h(float f) {
  union { ushort s; _Float16 h; } u; u.h = (_Float16)f; return u.s;
}
__device__ __forceinline__ float h2f(ushort s) {
  union { ushort s; _Float16 h; } u; u.s = s; return (float)u.h;
}
__device__ __forceinline__ void unpack2(uint v, float& a, float& b) {
  union { uint u; _Float16 h[2]; } x; x.u = v; a = (float)x.h[0]; b = (float)x.h[1];
}
__device__ __forceinline__ uint pack2(float a, float b) {
  union { uint u; _Float16 h[2]; } x; x.h[0] = (_Float16)a; x.h[1] = (_Float16)b; return x.u;
}
// split fp32 v into hi (fp16) and lo (fp16 of residual); v ≈ hi + lo with ~2^-22 rel err
__device__ __forceinline__ void split2(float a, float b, uint& hi, uint& lo) {
  float ah = h2f(f2h(a)), bh = h2f(f2h(b));
  hi = pack2(ah, bh);
  lo = pack2(a - ah, b - bh);
}
// pack one value's hi/lo fp16 into a single uint (hi in low 16, lo in high 16)
__device__ __forceinline__ uint packhl(float v) {
  ushort hi = f2h(v);
  ushort lo = f2h(v - h2f(hi));
  return (uint)hi | ((uint)lo << 16);
}
// acc += hi + lo of a packed element, one VALU op (v_dot2_f32_f16)
__device__ __forceinline__ float addhl(uint v, float acc) {
  union { uint u; f16x2 h; } x; x.u = v;
#if __has_builtin(__builtin_amdgcn_fdot2)
  const f16x2 one = {(_Float16)1.0f, (_Float16)1.0f};
  return __builtin_amdgcn_fdot2(x.h, one, acc, false);
#else
  return acc + (float)x.h[0] + (float)x.h[1];
#endif
}

// ---------------- async global->LDS (16B/lane) ----------------
__device__ __forceinline__ void gload_lds16(const ushort* g, ushort* l) {
  __builtin_amdgcn_global_load_lds(
      (const __attribute__((address_space(1))) void*)(const void*)g,
      (__attribute__((address_space(3))) void*)(void*)l,
      16, 0, 0);
}

// ---------------- edge-index width detection ----------------
__global__ void detect_idx_kernel(const int* __restrict__ idx, int twoE, int* flag) {
  __shared__ int ok;
  if (threadIdx.x == 0) ok = 1;
  __syncthreads();
  for (int i = threadIdx.x; i < 2048; i += blockDim.x) {
    int p = 2 * i + 1;
    if (p < twoE && idx[p] != 0) ok = 0;
  }
  __syncthreads();
  if (threadIdx.x == 0) flag[0] = ok;   // 1 => int64 storage, 0 => int32
}

__device__ __forceinline__ int edge_at(const int* __restrict__ idx, int pos, int is64) {
  return is64 ? idx[2 * pos] : idx[pos];
}

// ---------------- CSR build ----------------
__global__ void degree_kernel(const int* __restrict__ idx, int E, const int* __restrict__ flag,
                              int* __restrict__ row_start) {
  int e = blockIdx.x * blockDim.x + threadIdx.x;
  if (e >= E) return;
  int is64 = flag[0];
  int d = edge_at(idx, E + e, is64);
  atomicAdd(&row_start[d + 1], 1);
}

__global__ void scan_kernel(int* __restrict__ data, int n) {  // inclusive scan over n+1 entries
  __shared__ int sh[1024];
  __shared__ int carry;
  if (threadIdx.x == 0) carry = 0;
  __syncthreads();
  for (int base = 0; base < n + 1; base += 1024) {
    int i = base + threadIdx.x;
    int v = (i < n + 1) ? data[i] : 0;
    sh[threadIdx.x] = v;
    __syncthreads();
    for (int off = 1; off < 1024; off <<= 1) {
      int t = (threadIdx.x >= (unsigned)off) ? sh[threadIdx.x - off] : 0;
      __syncthreads();
      sh[threadIdx.x] += t;
      __syncthreads();
    }
    int inc = sh[threadIdx.x] + carry;
    if (i < n + 1) data[i] = inc;
    __syncthreads();
    if (threadIdx.x == 0) carry += sh[1023];
    __syncthreads();
  }
}

__global__ void scatter_kernel(const int* __restrict__ idx, int E, const int* __restrict__ flag,
                               const int* __restrict__ row_start, int* __restrict__ cursor,
                               int* __restrict__ csr) {
  int e = blockIdx.x * blockDim.x + threadIdx.x;
  if (e >= E) return;
  int is64 = flag[0];
  int s = edge_at(idx, e, is64);
  int d = edge_at(idx, E + e, is64);
  int pos = atomicAdd(&cursor[d], 1);
  csr[row_start[d] + pos] = s;
}

// ---------------- weight / input prep (fp32 -> fp16 hi/lo) ----------------
__global__ void prep_weights_kernel(const float* __restrict__ lin0_w, const float* __restrict__ w1,
                                    const float* __restrict__ w2, ushort* __restrict__ wH,
                                    ushort* __restrict__ wL, int totalw) {
  int i4 = (blockIdx.x * blockDim.x + threadIdx.x) * 4;
  if (i4 >= totalw) return;
  const int W = HQ * HQ;
  const float* src; int off;
  if (i4 < W)          { src = lin0_w; off = i4; }
  else if (i4 < 4 * W) { src = w1;     off = i4 - W; }
  else                 { src = w2;     off = i4 - 4 * W; }
  float4 v = *(const float4*)(src + off);
  uint2 ph, pl;
  split2(v.x, v.y, ph.x, pl.x);
  split2(v.z, v.w, ph.y, pl.y);
  *(uint2*)(wH + i4) = ph;
  *(uint2*)(wL + i4) = pl;
}

__global__ void prep_x_kernel(const float* __restrict__ x, ushort* __restrict__ xH,
                              ushort* __restrict__ xL, float* __restrict__ out0, int N, int MP) {
  int i4 = (blockIdx.x * blockDim.x + threadIdx.x) * 4;
  if (i4 >= MP * HQ) return;
  int row = i4 >> 9;
  uint2 ph, pl;
  if (row < N) {
    float4 v = *(const float4*)(x + i4);
    *(float4*)(out0 + i4) = v;                       // embs[0] = x (exact fp32 copy)
    split2(v.x, v.y, ph.x, pl.x);
    split2(v.z, v.w, ph.y, pl.y);
  } else {
    ph.x = ph.y = pl.x = pl.y = 0u;                  // zero pad rows
  }
  *(uint2*)(xH + i4) = ph;
  *(uint2*)(xL + i4) = pl;
}

// ---------------- GIN aggregation: z[n] = h[n] + sum_{j->n} h[j] ----------------
// h packed (hi|lo<<16). XCD-pinned column slice (slice = blockIdx.x, fastest dim).
// Edges processed in chunks of 8 (independent loads) to break the latency chain.
__global__ void gather_slice_kernel(const uint* __restrict__ hp, ushort* __restrict__ zH,
                                    ushort* __restrict__ zL, const int* __restrict__ row_start,
                                    const int* __restrict__ csr, int N) {
  const int slice = blockIdx.x;                 // 0..7
  const int sub   = threadIdx.x >> 5;           // 0..7 (node sub-group)
  const int l     = threadIdx.x & 31;
  const int n = blockIdx.y * 8 + sub;
  if (n >= N) return;
  const int c0 = slice * 64 + l * 2;
  const uint* hc = hp + c0;
  uint2 v = *(const uint2*)(hc + (size_t)n * HQ);
  float a0 = addhl(v.x, 0.f), a1 = addhl(v.y, 0.f);
  const int s = row_start[n], e = row_start[n + 1];
  for (int j = s; j < e; j += 8) {
    int  cc[8];
    bool ok[8];
#pragma unroll
    for (int k = 0; k < 8; ++k) {
      const int jj = j + k;
      ok[k] = jj < e;
      cc[k] = csr[ok[k] ? jj : s];
    }
    uint2 w[8];
#pragma unroll
    for (int k = 0; k < 8; ++k) w[k] = *(const uint2*)(hc + (size_t)cc[k] * HQ);
#pragma unroll
    for (int k = 0; k < 8; ++k) {
      const float t0 = addhl(w[k].x, a0);
      const float t1 = addhl(w[k].y, a1);
      a0 = ok[k] ? t0 : a0;
      a1 = ok[k] ? t1 : a1;
    }
  }
  ushort h0 = f2h(a0), h1 = f2h(a1);
  uint zh = (uint)h0 | ((uint)h1 << 16);
  uint zl = (uint)f2h(a0 - h2f(h0)) | ((uint)f2h(a1 - h2f(h1)) << 16);
  __builtin_nontemporal_store(zh, (uint*)(zH + (size_t)n * HQ + c0));
  __builtin_nontemporal_store(zl, (uint*)(zL + (size_t)n * HQ + c0));
}

// ---------------- GEMM: C[m,n] = A[m,:] . W[n,:] + bias[n], optional ReLU ----------------
// ROUND-7 KNOWN-GOOD STRUCTURE (458us total). 3-product double-fp16:
// C ≈ AH·WH + AL·WH + AH·WL, fp32 acc. 128x64 tile, BK=32, 4 waves (2x2 of 64x32),
// 2-phase double-buffered staging, 1 barrier/K-step, XCD-chunked 1D grid.
// STATS=1: per-column sum/sumsq (rows < Nvalid) -> LDS reduce -> one atomic/col/block.
// PACK=1: write packed hi|lo<<16 uints to CP instead of CH/CL planes.
template <int RELU, int STATS, int PACK>
__launch_bounds__(256)
__global__ void gemm3_kernel(const ushort* __restrict__ AH, const ushort* __restrict__ AL,
                             const ushort* __restrict__ WH, const ushort* __restrict__ WL,
                             const float* __restrict__ bias,
                             ushort* __restrict__ CH, ushort* __restrict__ CL,
                             uint* __restrict__ CP,
                             float* __restrict__ sums, int Nvalid, int MTm) {
  __shared__ ushort AsH[2][128 * 32];
  __shared__ ushort AsL[2][128 * 32];
  __shared__ ushort BsH[2][64 * 32];
  __shared__ ushort BsL[2][64 * 32];
  __shared__ float ssum[64];
  __shared__ float ssq[64];
  const int tid  = threadIdx.x;
  const int lane = tid & 63;
  const int wave = tid >> 6;

  // XCD-chunked swizzle (MTm divisible by 8; 8 n-tiles fastest within chunk)
  const int bid    = blockIdx.x;
  const int xcd    = bid & 7;
  const int local  = bid >> 3;
  const int chunk  = MTm >> 3;                 // m-tiles per XCD
  const int m_tile = xcd * chunk + (local >> 3);
  const int n_tile = local & 7;
  const int m0 = m_tile * 128;
  const int n0 = n_tile * 64;
  const int wm = (wave >> 1) * 64;             // wave row-half of the 128
  const int wn = (wave & 1) * 32;              // wave col-half of the 64

  if (STATS && tid < 64) { ssum[tid] = 0.f; ssq[tid] = 0.f; }

  f32x4 acc[4][2];
#pragma unroll
  for (int i = 0; i < 4; ++i)
#pragma unroll
    for (int j = 0; j < 2; ++j) acc[i][j] = (f32x4){0.f, 0.f, 0.f, 0.f};

  const int fr = lane & 15;
  const int kb = lane >> 4;
  const int srow = tid >> 2;          // staging: row = tid/4, col = (tid%4)*8
  const int scol = (tid & 3) * 8;

#define STAGE(buf, kt)                                                        \
  {                                                                           \
    const size_t ga0 = (size_t)(m0 + srow) * HQ + (kt) + scol;                \
    const size_t ga1 = ga0 + (size_t)64 * HQ;                                 \
    const size_t gb  = (size_t)(n0 + srow) * HQ + (kt) + scol;                \
    gload_lds16(AH + ga0, &AsH[buf][wave * 512]);                             \
    gload_lds16(AH + ga1, &AsH[buf][2048 + wave * 512]);                      \
    gload_lds16(AL + ga0, &AsL[buf][wave * 512]);                             \
    gload_lds16(AL + ga1, &AsL[buf][2048 + wave * 512]);                      \
    gload_lds16(WH + gb,  &BsH[buf][wave * 512]);                             \
    gload_lds16(WL + gb,  &BsL[buf][wave * 512]);                             \
  }

#define COMPUTE(buf)                                                          \
  {                                                                           \
    f16x8 afH[4], afL[4], bfH[2], bfL[2];                                     \
    _Pragma("unroll")                                                         \
    for (int i = 0; i < 4; ++i) {                                             \
      afH[i] = *(const f16x8*)&AsH[buf][(wm + i * 16 + fr) * 32 + kb * 8];    \
      afL[i] = *(const f16x8*)&AsL[buf][(wm + i * 16 + fr) * 32 + kb * 8];    \
    }                                                                         \
    _Pragma("unroll")                                                         \
    for (int j = 0; j < 2; ++j) {                                             \
      bfH[j] = *(const f16x8*)&BsH[buf][(wn + j * 16 + fr) * 32 + kb * 8];    \
      bfL[j] = *(const f16x8*)&BsL[buf][(wn + j * 16 + fr) * 32 + kb * 8];    \
    }                                                                         \
    _Pragma("unroll")                                                         \
    for (int i = 0; i < 4; ++i)                                               \
      _Pragma("unroll")                                                       \
      for (int j = 0; j < 2; ++j)                                             \
        acc[i][j] = __builtin_amdgcn_mfma_f32_16x16x32_f16(afH[i], bfH[j], acc[i][j], 0, 0, 0); \
    _Pragma("unroll")                                                         \
    for (int i = 0; i < 4; ++i)                                               \
      _Pragma("unroll")                                                       \
      for (int j = 0; j < 2; ++j)                                             \
        acc[i][j] = __builtin_amdgcn_mfma_f32_16x16x32_f16(afL[i], bfH[j], acc[i][j], 0, 0, 0); \
    _Pragma("unroll")                                                         \
    for (int i = 0; i < 4; ++i)                                               \
      _Pragma("unroll")                                                       \
      for (int j = 0; j < 2; ++j)                                             \
        acc[i][j] = __builtin_amdgcn_mfma_f32_16x16x32_f16(afH[i], bfL[j], acc[i][j], 0, 0, 0); \
  }

  STAGE(0, 0);
  __syncthreads();                     // drains vmcnt(0): tile 0 resident
  int cur = 0;
  for (int kt = 32; kt < HQ; kt += 32) {
    STAGE(cur ^ 1, kt);                // issue next-tile loads first (fly during MFMA)
    COMPUTE(cur);
    __syncthreads();                   // vmcnt(0)+lgkmcnt(0)+barrier: next tile ready, cur free
    cur ^= 1;
  }
  COMPUTE(cur);
#undef STAGE
#undef COMPUTE

  // epilogue: D col = lane&15, row = (lane>>4)*4 + r   [guide §3, m89/m91-verified]
#pragma unroll
  for (int j = 0; j < 2; ++j) {
    const int col = n0 + wn + j * 16 + fr;
    const float b = bias[col];
    float cs = 0.f, cq = 0.f;
#pragma unroll
    for (int i = 0; i < 4; ++i) {
      const int mb = m0 + wm + i * 16 + kb * 4;
#pragma unroll
      for (int r = 0; r < 4; ++r) {
        float v = acc[i][j][r] + b;
        if (RELU) v = fmaxf(v, 0.f);
        if (STATS) {
          const float vm = (mb + r < Nvalid) ? v : 0.f;
          cs += vm;
          cq += vm * vm;
        }
        const size_t oidx = (size_t)(mb + r) * HQ + col;
        if (PACK) {
          CP[oidx] = packhl(v);
        } else {
          ushort hi = f2h(v);
          CH[oidx] = hi;
          CL[oidx] = f2h(v - h2f(hi));
        }
      }
    }
    if (STATS) {
      // reduce across the 4 kb lanes (same fr/col): lane ids differ in bits 4,5
      cs += __shfl_xor(cs, 16); cq += __shfl_xor(cq, 16);
      cs += __shfl_xor(cs, 32); cq += __shfl_xor(cq, 32);
      if (kb == 0) {
        atomicAdd(&ssum[wn + j * 16 + fr], cs);
        atomicAdd(&ssq[wn + j * 16 + fr], cq);
      }
    }
  }
  if (STATS) {
    __syncthreads();
    if (tid < 64) {
      atomicAdd(&sums[n0 + tid], ssum[tid]);
      atomicAdd(&sums[HQ + n0 + tid], ssq[tid]);
    }
  }
}

// ---------------- BatchNorm finalize+apply+tanh, XCD-aligned with gather ----------------
// Grid (8 slices fastest, row-blocks): block (s, rb) handles cols s*64..s*64+63 of rows
// rb*32..rb*32+31. Slice s lands on XCD s (same mapping as gather_slice), so the packed
// h written here is L2-resident for the NEXT layer's gather on the same XCD.
// Finalize fused: threads 0..63 compute this slice's scale/shift into LDS.
__global__ void bn_apply_tanh_kernel(const ushort* __restrict__ zH, const ushort* __restrict__ zL,
                                     const float* __restrict__ sums, const float* __restrict__ gamma,
                                     const float* __restrict__ beta, float* __restrict__ outp,
                                     uint* __restrict__ hp, int N) {
  __shared__ float lsc[64];
  __shared__ float lsh[64];
  const int tid = threadIdx.x;
  const int s   = blockIdx.x;                   // slice 0..7 (fastest -> XCD s)
  if (tid < 64) {
    const int c = s * 64 + tid;
    const float inv_n = 1.f / (float)N;
    const float mu  = sums[c] * inv_n;
    const float var = fmaxf(sums[HQ + c] * inv_n - mu * mu, 0.f);
    const float sc  = gamma[c] * rsqrtf(var + BN_EPS);
    lsc[tid] = sc;
    lsh[tid] = beta[c] - mu * sc;
  }
  __syncthreads();
  const int r = blockIdx.y * 32 + (tid >> 3);
  if (r >= N) return;
  const int cL = (tid & 7) * 8;                 // local col 0..56
  const size_t base = (size_t)r * HQ + s * 64 + cL;
  uint4 vh = *(const uint4*)(zH + base);
  uint4 vl = *(const uint4*)(zL + base);
  float a[8];
  {
    float t0, t1, u0, u1;
    unpack2(vh.x, t0, t1); unpack2(vl.x, u0, u1); a[0] = t0 + u0; a[1] = t1 + u1;
    unpack2(vh.y, t0, t1); unpack2(vl.y, u0, u1); a[2] = t0 + u0; a[3] = t1 + u1;
    unpack2(vh.z, t0, t1); unpack2(vl.z, u0, u1); a[4] = t0 + u0; a[5] = t1 + u1;
    unpack2(vh.w, t0, t1); unpack2(vl.w, u0, u1); a[6] = t0 + u0; a[7] = t1 + u1;
  }
  float4 sA = *(const float4*)&lsc[cL];
  float4 sB = *(const float4*)&lsc[cL + 4];
  float4 hA = *(const float4*)&lsh[cL];
  float4 hB = *(const float4*)&lsh[cL + 4];
  float y[8];
  y[0] = tanhf(fmaf(a[0], sA.x, hA.x));
  y[1] = tanhf(fmaf(a[1], sA.y, hA.y));
  y[2] = tanhf(fmaf(a[2], sA.z, hA.z));
  y[3] = tanhf(fmaf(a[3], sA.w, hA.w));
  y[4] = tanhf(fmaf(a[4], sB.x, hB.x));
  y[5] = tanhf(fmaf(a[5], sB.y, hB.y));
  y[6] = tanhf(fmaf(a[6], sB.z, hB.z));
  y[7] = tanhf(fmaf(a[7], sB.w, hB.w));
  *(float4*)(outp + base)     = make_float4(y[0], y[1], y[2], y[3]);
  *(float4*)(outp + base + 4) = make_float4(y[4], y[5], y[6], y[7]);
  uint4 p0, p1;
  p0.x = packhl(y[0]); p0.y = packhl(y[1]); p0.z = packhl(y[2]); p0.w = packhl(y[3]);
  p1.x = packhl(y[4]); p1.y = packhl(y[5]); p1.z = packhl(y[6]); p1.w = packhl(y[7]);
  *(uint4*)(hp + base)     = p0;
  *(uint4*)(hp + base + 4) = p1;
}

// ---------------- launcher ----------------
extern "C" void kernel_launch(void* const* d_in, const int* in_sizes, int n_in,
                              void* d_out, int out_size, void* d_ws, size_t ws_size,
                              hipStream_t stream) {
  const float* x      = (const float*)d_in[0];
  const int*   idx    = (const int*)  d_in[1];
  const float* lin0_w = (const float*)d_in[2];
  const float* lin0_b = (const float*)d_in[3];
  const float* w1     = (const float*)d_in[4];
  const float* b1     = (const float*)d_in[5];
  const float* w2     = (const float*)d_in[6];
  const float* b2     = (const float*)d_in[7];
  const float* gamma  = (const float*)d_in[8];
  const float* beta   = (const float*)d_in[9];
  float* out = (float*)d_out;

  const int N    = in_sizes[0] / HQ;           // 10000
  const int twoE = in_sizes[1];                // 2*E
  const int E    = twoE / 2;
  const int L    = in_sizes[4] / (HQ * HQ);    // 3
  // pad M so 128-row m-tiles divide into 8 XCD chunks: MP = 10240, MTm = 80
  const int MP   = ((N + 1023) / 1024) * 1024;
  const int MTm  = MP / 128;
  const size_t NH = (size_t)N * HQ;
  const size_t T  = (size_t)MP * HQ;           // padded tensor elems

  // workspace carve (all 16B-aligned)
  char* wsp = (char*)d_ws;
  int*    flag  = (int*)wsp;
  uint*   hbP   = (uint*)(wsp + 256);          // packed h (hi|lo<<16), T uints
  ushort* zAH   = (ushort*)(hbP + T);
  ushort* zAL   = zAH + T;
  ushort* zBH   = zAL + T;
  ushort* zBL   = zBH + T;
  ushort* wHp   = zBL + T;
  ushort* wLp   = wHp + (size_t)(1 + 2 * L) * HQ * HQ;
  int*    row_start = (int*)(wLp + (size_t)(1 + 2 * L) * HQ * HQ);
  int*    cursor    = row_start + (N + 1);
  int*    csr       = cursor + N;
  float*  bnsums    = (float*)(csr + E);       // 3 layers x 2*HQ

  hipMemsetAsync(row_start, 0, (size_t)(2 * N + 1) * sizeof(int), stream);
  hipMemsetAsync(bnsums, 0, 6 * HQ * sizeof(float), stream);
  detect_idx_kernel<<<1, 256, 0, stream>>>(idx, twoE, flag);

  const int totalw = (1 + 2 * L) * HQ * HQ;
  prep_weights_kernel<<<(totalw / 4 + 255) / 256, 256, 0, stream>>>(lin0_w, w1, w2, wHp, wLp, totalw);
  prep_x_kernel<<<((int)(T / 4) + 255) / 256, 256, 0, stream>>>(x, zAH, zAL, out, N, MP);

  degree_kernel<<<(E + 255) / 256, 256, 0, stream>>>(idx, E, flag, row_start);
  scan_kernel<<<1, 1024, 0, stream>>>(row_start, N);
  scatter_kernel<<<(E + 255) / 256, 256, 0, stream>>>(idx, E, flag, row_start, cursor, csr);

  const int ggrid = MTm * 8;                   // 640 blocks, 1D (XCD swizzle inside)

  // h0 = x @ lin0_w.T + lin0_b   (no activation), packed output
  gemm3_kernel<0, 0, 1><<<ggrid, 256, 0, stream>>>(
      zAH, zAL, wHp, wLp, lin0_b, nullptr, nullptr, hbP, nullptr, N, MTm);

  for (int l = 0; l < L; ++l) {
    gather_slice_kernel<<<dim3(HQ / 64, (N + 7) / 8), 256, 0, stream>>>(
        hbP, zAH, zAL, row_start, csr, N);
    gemm3_kernel<1, 0, 0><<<ggrid, 256, 0, stream>>>(
        zAH, zAL, wHp + (size_t)(1 + l) * HQ * HQ, wLp + (size_t)(1 + l) * HQ * HQ,
        b1 + (size_t)l * HQ, zBH, zBL, nullptr, nullptr, N, MTm);
    gemm3_kernel<1, 1, 0><<<ggrid, 256, 0, stream>>>(
        zBH, zBL, wHp + (size_t)(1 + L + l) * HQ * HQ, wLp + (size_t)(1 + L + l) * HQ * HQ,
        b2 + (size_t)l * HQ, zAH, zAL, nullptr, bnsums + 2 * HQ * l, N, MTm);
    bn_apply_tanh_kernel<<<dim3(HQ / 64, (N + 31) / 32), 256, 0, stream>>>(
        zAH, zAL, bnsums + 2 * HQ * l, gamma + (size_t)l * HQ, beta + (size_t)l * HQ,
        out + (size_t)(l + 1) * NH, hbP, N);
  }
}

// Round 12
// 434.164 us; speedup vs baseline: 1.6668x; 1.0474x over previous
//
#include <hip/hip_runtime.h>

typedef unsigned int uint;
typedef unsigned short ushort;
typedef __attribute__((ext_vector_type(4))) float f32x4;
typedef __attribute__((ext_vector_type(8))) _Float16 f16x8;
typedef __attribute__((ext_vector_type(2))) _Float16 f16x2;

#define HQ 512
#define BN_EPS 1e-5f

// ---------------- fp16 <-> fp32 helpers ----------------
__device__ __forceinline__ ushort f2h(float f) {
  union { ushort s; _Float16 h; } u; u.h = (_Float16)f; return u.s;
}
__device__ __forceinline__ float h2f(ushort s) {
  union { ushort s; _Float16 h; } u; u.s = s; return (float)u.h;
}
__device__ __forceinline__ void unpack2(uint v, float& a, float& b) {
  union { uint u; _Float16 h[2]; } x; x.u = v; a = (float)x.h[0]; b = (float)x.h[1];
}
__device__ __forceinline__ uint pack2(float a, float b) {
  union { uint u; _Float16 h[2]; } x; x.h[0] = (_Float16)a; x.h[1] = (_Float16)b; return x.u;
}
// split fp32 v into hi (fp16) and lo (fp16 of residual); v ≈ hi + lo with ~2^-22 rel err
__device__ __forceinline__ void split2(float a, float b, uint& hi, uint& lo) {
  float ah = h2f(f2h(a)), bh = h2f(f2h(b));
  hi = pack2(ah, bh);
  lo = pack2(a - ah, b - bh);
}
// pack one value's hi/lo fp16 into a single uint (hi in low 16, lo in high 16)
__device__ __forceinline__ uint packhl(float v) {
  ushort hi = f2h(v);
  ushort lo = f2h(v - h2f(hi));
  return (uint)hi | ((uint)lo << 16);
}
// acc += hi + lo of a packed element, one VALU op (v_dot2_f32_f16)
__device__ __forceinline__ float addhl(uint v, float acc) {
  union { uint u; f16x2 h; } x; x.u = v;
#if __has_builtin(__builtin_amdgcn_fdot2)
  const f16x2 one = {(_Float16)1.0f, (_Float16)1.0f};
  return __builtin_amdgcn_fdot2(x.h, one, acc, false);
#else
  return acc + (float)x.h[0] + (float)x.h[1];
#endif
}

// ---------------- async global->LDS (16B/lane) ----------------
__device__ __forceinline__ void gload_lds16(const ushort* g, ushort* l) {
  __builtin_amdgcn_global_load_lds(
      (const __attribute__((address_space(1))) void*)(const void*)g,
      (__attribute__((address_space(3))) void*)(void*)l,
      16, 0, 0);
}

// ---------------- edge-index width detection ----------------
__global__ void detect_idx_kernel(const int* __restrict__ idx, int twoE, int* flag) {
  __shared__ int ok;
  if (threadIdx.x == 0) ok = 1;
  __syncthreads();
  for (int i = threadIdx.x; i < 2048; i += blockDim.x) {
    int p = 2 * i + 1;
    if (p < twoE && idx[p] != 0) ok = 0;
  }
  __syncthreads();
  if (threadIdx.x == 0) flag[0] = ok;   // 1 => int64 storage, 0 => int32
}

__device__ __forceinline__ int edge_at(const int* __restrict__ idx, int pos, int is64) {
  return is64 ? idx[2 * pos] : idx[pos];
}

// ---------------- CSR build ----------------
__global__ void degree_kernel(const int* __restrict__ idx, int E, const int* __restrict__ flag,
                              int* __restrict__ row_start) {
  int e = blockIdx.x * blockDim.x + threadIdx.x;
  if (e >= E) return;
  int is64 = flag[0];
  int d = edge_at(idx, E + e, is64);
  atomicAdd(&row_start[d + 1], 1);
}

__global__ void scan_kernel(int* __restrict__ data, int n) {  // inclusive scan over n+1 entries
  __shared__ int sh[1024];
  __shared__ int carry;
  if (threadIdx.x == 0) carry = 0;
  __syncthreads();
  for (int base = 0; base < n + 1; base += 1024) {
    int i = base + threadIdx.x;
    int v = (i < n + 1) ? data[i] : 0;
    sh[threadIdx.x] = v;
    __syncthreads();
    for (int off = 1; off < 1024; off <<= 1) {
      int t = (threadIdx.x >= (unsigned)off) ? sh[threadIdx.x - off] : 0;
      __syncthreads();
      sh[threadIdx.x] += t;
      __syncthreads();
    }
    int inc = sh[threadIdx.x] + carry;
    if (i < n + 1) data[i] = inc;
    __syncthreads();
    if (threadIdx.x == 0) carry += sh[1023];
    __syncthreads();
  }
}

__global__ void scatter_kernel(const int* __restrict__ idx, int E, const int* __restrict__ flag,
                               const int* __restrict__ row_start, int* __restrict__ cursor,
                               int* __restrict__ csr) {
  int e = blockIdx.x * blockDim.x + threadIdx.x;
  if (e >= E) return;
  int is64 = flag[0];
  int s = edge_at(idx, e, is64);
  int d = edge_at(idx, E + e, is64);
  int pos = atomicAdd(&cursor[d], 1);
  csr[row_start[d] + pos] = s;
}

// ---------------- weight / input prep (fp32 -> fp16 hi/lo) ----------------
__global__ void prep_weights_kernel(const float* __restrict__ lin0_w, const float* __restrict__ w1,
                                    const float* __restrict__ w2, ushort* __restrict__ wH,
                                    ushort* __restrict__ wL, int totalw) {
  int i4 = (blockIdx.x * blockDim.x + threadIdx.x) * 4;
  if (i4 >= totalw) return;
  const int W = HQ * HQ;
  const float* src; int off;
  if (i4 < W)          { src = lin0_w; off = i4; }
  else if (i4 < 4 * W) { src = w1;     off = i4 - W; }
  else                 { src = w2;     off = i4 - 4 * W; }
  float4 v = *(const float4*)(src + off);
  uint2 ph, pl;
  split2(v.x, v.y, ph.x, pl.x);
  split2(v.z, v.w, ph.y, pl.y);
  *(uint2*)(wH + i4) = ph;
  *(uint2*)(wL + i4) = pl;
}

__global__ void prep_x_kernel(const float* __restrict__ x, ushort* __restrict__ xH,
                              ushort* __restrict__ xL, float* __restrict__ out0, int N, int MP) {
  int i4 = (blockIdx.x * blockDim.x + threadIdx.x) * 4;
  if (i4 >= MP * HQ) return;
  int row = i4 >> 9;
  uint2 ph, pl;
  if (row < N) {
    float4 v = *(const float4*)(x + i4);
    *(float4*)(out0 + i4) = v;                       // embs[0] = x (exact fp32 copy)
    split2(v.x, v.y, ph.x, pl.x);
    split2(v.z, v.w, ph.y, pl.y);
  } else {
    ph.x = ph.y = pl.x = pl.y = 0u;                  // zero pad rows
  }
  *(uint2*)(xH + i4) = ph;
  *(uint2*)(xL + i4) = pl;
}

// ---------------- GIN aggregation: z[n] = h[n] + sum_{j->n} h[j] ----------------
// h packed (hi|lo<<16). XCD-pinned column slice (slice = blockIdx.x, fastest dim).
// SCALAR-IZED: 1 wave = 1 node (64 lanes x 1 col), so row_start / loop bounds /
// csr indices are wave-uniform -> readfirstlane forces them into SGPRs; csr reads
// become s_load and row loads use scalar bases (SALU does the address math, VALU
// per edge/lane is ~1 v_dot2 + 1 load). 8-edge chunks keep loads independent.
__global__ void gather_slice_kernel(const uint* __restrict__ hp, ushort* __restrict__ zH,
                                    ushort* __restrict__ zL, const int* __restrict__ row_start,
                                    const int* __restrict__ csr, int N) {
  const int slice = blockIdx.x;                 // 0..7 (fastest -> XCD s)
  const int wave  = threadIdx.x >> 6;           // 0..3
  const int lane  = threadIdx.x & 63;
  const int n = blockIdx.y * 4 + wave;
  if (n >= N) return;
  const int col = slice * 64 + lane;
  const uint* hc = hp + col;
  float a = addhl(hc[(size_t)n * HQ], 0.f);
  const int s = __builtin_amdgcn_readfirstlane(row_start[n]);
  const int e = __builtin_amdgcn_readfirstlane(row_start[n + 1]);
  for (int j = s; j < e; j += 8) {
    int  cc[8];
    bool ok[8];
#pragma unroll
    for (int k = 0; k < 8; ++k) {
      const int jj = j + k;
      ok[k] = jj < e;
      cc[k] = __builtin_amdgcn_readfirstlane(csr[ok[k] ? jj : s]);
    }
    uint w[8];
#pragma unroll
    for (int k = 0; k < 8; ++k) w[k] = hc[(size_t)cc[k] * HQ];
#pragma unroll
    for (int k = 0; k < 8; ++k) {
      const float t = addhl(w[k], a);
      a = ok[k] ? t : a;
    }
  }
  ushort h0 = f2h(a);
  zH[(size_t)n * HQ + col] = h0;
  zL[(size_t)n * HQ + col] = f2h(a - h2f(h0));
}

// ---------------- GEMM: C[m,n] = A[m,:] . W[n,:] + bias[n], optional ReLU ----------------
// ROUND-7/11 KNOWN-GOOD STRUCTURE. 3-product double-fp16:
// C ≈ AH·WH + AL·WH + AH·WL, fp32 acc. 128x64 tile, BK=32, 4 waves (2x2 of 64x32),
// 2-phase double-buffered staging, 1 barrier/K-step, XCD-chunked 1D grid.
// STATS=1: per-column sum/sumsq (rows < Nvalid) -> LDS reduce -> one atomic/col/block.
// PACK=1: write packed hi|lo<<16 uints to CP instead of CH/CL planes.
template <int RELU, int STATS, int PACK>
__launch_bounds__(256)
__global__ void gemm3_kernel(const ushort* __restrict__ AH, const ushort* __restrict__ AL,
                             const ushort* __restrict__ WH, const ushort* __restrict__ WL,
                             const float* __restrict__ bias,
                             ushort* __restrict__ CH, ushort* __restrict__ CL,
                             uint* __restrict__ CP,
                             float* __restrict__ sums, int Nvalid, int MTm) {
  __shared__ ushort AsH[2][128 * 32];
  __shared__ ushort AsL[2][128 * 32];
  __shared__ ushort BsH[2][64 * 32];
  __shared__ ushort BsL[2][64 * 32];
  __shared__ float ssum[64];
  __shared__ float ssq[64];
  const int tid  = threadIdx.x;
  const int lane = tid & 63;
  const int wave = tid >> 6;

  // XCD-chunked swizzle (MTm divisible by 8; 8 n-tiles fastest within chunk)
  const int bid    = blockIdx.x;
  const int xcd    = bid & 7;
  const int local  = bid >> 3;
  const int chunk  = MTm >> 3;                 // m-tiles per XCD
  const int m_tile = xcd * chunk + (local >> 3);
  const int n_tile = local & 7;
  const int m0 = m_tile * 128;
  const int n0 = n_tile * 64;
  const int wm = (wave >> 1) * 64;             // wave row-half of the 128
  const int wn = (wave & 1) * 32;              // wave col-half of the 64

  if (STATS && tid < 64) { ssum[tid] = 0.f; ssq[tid] = 0.f; }

  f32x4 acc[4][2];
#pragma unroll
  for (int i = 0; i < 4; ++i)
#pragma unroll
    for (int j = 0; j < 2; ++j) acc[i][j] = (f32x4){0.f, 0.f, 0.f, 0.f};

  const int fr = lane & 15;
  const int kb = lane >> 4;
  const int srow = tid >> 2;          // staging: row = tid/4, col = (tid%4)*8
  const int scol = (tid & 3) * 8;

#define STAGE(buf, kt)                                                        \
  {                                                                           \
    const size_t ga0 = (size_t)(m0 + srow) * HQ + (kt) + scol;                \
    const size_t ga1 = ga0 + (size_t)64 * HQ;                                 \
    const size_t gb  = (size_t)(n0 + srow) * HQ + (kt) + scol;                \
    gload_lds16(AH + ga0, &AsH[buf][wave * 512]);                             \
    gload_lds16(AH + ga1, &AsH[buf][2048 + wave * 512]);                      \
    gload_lds16(AL + ga0, &AsL[buf][wave * 512]);                             \
    gload_lds16(AL + ga1, &AsL[buf][2048 + wave * 512]);                      \
    gload_lds16(WH + gb,  &BsH[buf][wave * 512]);                             \
    gload_lds16(WL + gb,  &BsL[buf][wave * 512]);                             \
  }

#define COMPUTE(buf)                                                          \
  {                                                                           \
    f16x8 afH[4], afL[4], bfH[2], bfL[2];                                     \
    _Pragma("unroll")                                                         \
    for (int i = 0; i < 4; ++i) {                                             \
      afH[i] = *(const f16x8*)&AsH[buf][(wm + i * 16 + fr) * 32 + kb * 8];    \
      afL[i] = *(const f16x8*)&AsL[buf][(wm + i * 16 + fr) * 32 + kb * 8];    \
    }                                                                         \
    _Pragma("unroll")                                                         \
    for (int j = 0; j < 2; ++j) {                                             \
      bfH[j] = *(const f16x8*)&BsH[buf][(wn + j * 16 + fr) * 32 + kb * 8];    \
      bfL[j] = *(const f16x8*)&BsL[buf][(wn + j * 16 + fr) * 32 + kb * 8];    \
    }                                                                         \
    _Pragma("unroll")                                                         \
    for (int i = 0; i < 4; ++i)                                               \
      _Pragma("unroll")                                                       \
      for (int j = 0; j < 2; ++j)                                             \
        acc[i][j] = __builtin_amdgcn_mfma_f32_16x16x32_f16(afH[i], bfH[j], acc[i][j], 0, 0, 0); \
    _Pragma("unroll")                                                         \
    for (int i = 0; i < 4; ++i)                                               \
      _Pragma("unroll")                                                       \
      for (int j = 0; j < 2; ++j)                                             \
        acc[i][j] = __builtin_amdgcn_mfma_f32_16x16x32_f16(afL[i], bfH[j], acc[i][j], 0, 0, 0); \
    _Pragma("unroll")                                                         \
    for (int i = 0; i < 4; ++i)                                               \
      _Pragma("unroll")                                                       \
      for (int j = 0; j < 2; ++j)                                             \
        acc[i][j] = __builtin_amdgcn_mfma_f32_16x16x32_f16(afH[i], bfL[j], acc[i][j], 0, 0, 0); \
  }

  STAGE(0, 0);
  __syncthreads();                     // drains vmcnt(0): tile 0 resident
  int cur = 0;
  for (int kt = 32; kt < HQ; kt += 32) {
    STAGE(cur ^ 1, kt);                // issue next-tile loads first (fly during MFMA)
    COMPUTE(cur);
    __syncthreads();                   // vmcnt(0)+lgkmcnt(0)+barrier: next tile ready, cur free
    cur ^= 1;
  }
  COMPUTE(cur);
#undef STAGE
#undef COMPUTE

  // epilogue: D col = lane&15, row = (lane>>4)*4 + r   [guide §3, m89/m91-verified]
#pragma unroll
  for (int j = 0; j < 2; ++j) {
    const int col = n0 + wn + j * 16 + fr;
    const float b = bias[col];
    float cs = 0.f, cq = 0.f;
#pragma unroll
    for (int i = 0; i < 4; ++i) {
      const int mb = m0 + wm + i * 16 + kb * 4;
#pragma unroll
      for (int r = 0; r < 4; ++r) {
        float v = acc[i][j][r] + b;
        if (RELU) v = fmaxf(v, 0.f);
        if (STATS) {
          const float vm = (mb + r < Nvalid) ? v : 0.f;
          cs += vm;
          cq += vm * vm;
        }
        const size_t oidx = (size_t)(mb + r) * HQ + col;
        if (PACK) {
          CP[oidx] = packhl(v);
        } else {
          ushort hi = f2h(v);
          CH[oidx] = hi;
          CL[oidx] = f2h(v - h2f(hi));
        }
      }
    }
    if (STATS) {
      // reduce across the 4 kb lanes (same fr/col): lane ids differ in bits 4,5
      cs += __shfl_xor(cs, 16); cq += __shfl_xor(cq, 16);
      cs += __shfl_xor(cs, 32); cq += __shfl_xor(cq, 32);
      if (kb == 0) {
        atomicAdd(&ssum[wn + j * 16 + fr], cs);
        atomicAdd(&ssq[wn + j * 16 + fr], cq);
      }
    }
  }
  if (STATS) {
    __syncthreads();
    if (tid < 64) {
      atomicAdd(&sums[n0 + tid], ssum[tid]);
      atomicAdd(&sums[HQ + n0 + tid], ssq[tid]);
    }
  }
}

// ---------------- BatchNorm finalize+apply+tanh, XCD-aligned with gather ----------------
// Grid (8 slices fastest, row-blocks): block (s, rb) handles cols s*64..s*64+63 of rows
// rb*32..rb*32+31. Slice s lands on XCD s (same mapping as gather_slice), so the packed
// h written here is L2-resident for the NEXT layer's gather on the same XCD.
// Finalize fused: threads 0..63 compute this slice's scale/shift into LDS.
__global__ void bn_apply_tanh_kernel(const ushort* __restrict__ zH, const ushort* __restrict__ zL,
                                     const float* __restrict__ sums, const float* __restrict__ gamma,
                                     const float* __restrict__ beta, float* __restrict__ outp,
                                     uint* __restrict__ hp, int N) {
  __shared__ float lsc[64];
  __shared__ float lsh[64];
  const int tid = threadIdx.x;
  const int s   = blockIdx.x;                   // slice 0..7 (fastest -> XCD s)
  if (tid < 64) {
    const int c = s * 64 + tid;
    const float inv_n = 1.f / (float)N;
    const float mu  = sums[c] * inv_n;
    const float var = fmaxf(sums[HQ + c] * inv_n - mu * mu, 0.f);
    const float sc  = gamma[c] * rsqrtf(var + BN_EPS);
    lsc[tid] = sc;
    lsh[tid] = beta[c] - mu * sc;
  }
  __syncthreads();
  const int r = blockIdx.y * 32 + (tid >> 3);
  if (r >= N) return;
  const int cL = (tid & 7) * 8;                 // local col 0..56
  const size_t base = (size_t)r * HQ + s * 64 + cL;
  uint4 vh = *(const uint4*)(zH + base);
  uint4 vl = *(const uint4*)(zL + base);
  float a[8];
  {
    float t0, t1, u0, u1;
    unpack2(vh.x, t0, t1); unpack2(vl.x, u0, u1); a[0] = t0 + u0; a[1] = t1 + u1;
    unpack2(vh.y, t0, t1); unpack2(vl.y, u0, u1); a[2] = t0 + u0; a[3] = t1 + u1;
    unpack2(vh.z, t0, t1); unpack2(vl.z, u0, u1); a[4] = t0 + u0; a[5] = t1 + u1;
    unpack2(vh.w, t0, t1); unpack2(vl.w, u0, u1); a[6] = t0 + u0; a[7] = t1 + u1;
  }
  float4 sA = *(const float4*)&lsc[cL];
  float4 sB = *(const float4*)&lsc[cL + 4];
  float4 hA = *(const float4*)&lsh[cL];
  float4 hB = *(const float4*)&lsh[cL + 4];
  float y[8];
  y[0] = tanhf(fmaf(a[0], sA.x, hA.x));
  y[1] = tanhf(fmaf(a[1], sA.y, hA.y));
  y[2] = tanhf(fmaf(a[2], sA.z, hA.z));
  y[3] = tanhf(fmaf(a[3], sA.w, hA.w));
  y[4] = tanhf(fmaf(a[4], sB.x, hB.x));
  y[5] = tanhf(fmaf(a[5], sB.y, hB.y));
  y[6] = tanhf(fmaf(a[6], sB.z, hB.z));
  y[7] = tanhf(fmaf(a[7], sB.w, hB.w));
  *(float4*)(outp + base)     = make_float4(y[0], y[1], y[2], y[3]);
  *(float4*)(outp + base + 4) = make_float4(y[4], y[5], y[6], y[7]);
  uint4 p0, p1;
  p0.x = packhl(y[0]); p0.y = packhl(y[1]); p0.z = packhl(y[2]); p0.w = packhl(y[3]);
  p1.x = packhl(y[4]); p1.y = packhl(y[5]); p1.z = packhl(y[6]); p1.w = packhl(y[7]);
  *(uint4*)(hp + base)     = p0;
  *(uint4*)(hp + base + 4) = p1;
}

// ---------------- launcher ----------------
extern "C" void kernel_launch(void* const* d_in, const int* in_sizes, int n_in,
                              void* d_out, int out_size, void* d_ws, size_t ws_size,
                              hipStream_t stream) {
  const float* x      = (const float*)d_in[0];
  const int*   idx    = (const int*)  d_in[1];
  const float* lin0_w = (const float*)d_in[2];
  const float* lin0_b = (const float*)d_in[3];
  const float* w1     = (const float*)d_in[4];
  const float* b1     = (const float*)d_in[5];
  const float* w2     = (const float*)d_in[6];
  const float* b2     = (const float*)d_in[7];
  const float* gamma  = (const float*)d_in[8];
  const float* beta   = (const float*)d_in[9];
  float* out = (float*)d_out;

  const int N    = in_sizes[0] / HQ;           // 10000
  const int twoE = in_sizes[1];                // 2*E
  const int E    = twoE / 2;
  const int L    = in_sizes[4] / (HQ * HQ);    // 3
  // pad M so 128-row m-tiles divide into 8 XCD chunks: MP = 10240, MTm = 80
  const int MP   = ((N + 1023) / 1024) * 1024;
  const int MTm  = MP / 128;
  const size_t NH = (size_t)N * HQ;
  const size_t T  = (size_t)MP * HQ;           // padded tensor elems

  // workspace carve (all 16B-aligned)
  char* wsp = (char*)d_ws;
  int*    flag  = (int*)wsp;
  uint*   hbP   = (uint*)(wsp + 256);          // packed h (hi|lo<<16), T uints
  ushort* zAH   = (ushort*)(hbP + T);
  ushort* zAL   = zAH + T;
  ushort* zBH   = zAL + T;
  ushort* zBL   = zBH + T;
  ushort* wHp   = zBL + T;
  ushort* wLp   = wHp + (size_t)(1 + 2 * L) * HQ * HQ;
  int*    row_start = (int*)(wLp + (size_t)(1 + 2 * L) * HQ * HQ);
  int*    cursor    = row_start + (N + 1);
  int*    csr       = cursor + N;
  float*  bnsums    = (float*)(csr + E);       // 3 layers x 2*HQ

  hipMemsetAsync(row_start, 0, (size_t)(2 * N + 1) * sizeof(int), stream);
  hipMemsetAsync(bnsums, 0, 6 * HQ * sizeof(float), stream);
  detect_idx_kernel<<<1, 256, 0, stream>>>(idx, twoE, flag);

  const int totalw = (1 + 2 * L) * HQ * HQ;
  prep_weights_kernel<<<(totalw / 4 + 255) / 256, 256, 0, stream>>>(lin0_w, w1, w2, wHp, wLp, totalw);
  prep_x_kernel<<<((int)(T / 4) + 255) / 256, 256, 0, stream>>>(x, zAH, zAL, out, N, MP);

  degree_kernel<<<(E + 255) / 256, 256, 0, stream>>>(idx, E, flag, row_start);
  scan_kernel<<<1, 1024, 0, stream>>>(row_start, N);
  scatter_kernel<<<(E + 255) / 256, 256, 0, stream>>>(idx, E, flag, row_start, cursor, csr);

  const int ggrid = MTm * 8;                   // 640 blocks, 1D (XCD swizzle inside)

  // h0 = x @ lin0_w.T + lin0_b   (no activation), packed output
  gemm3_kernel<0, 0, 1><<<ggrid, 256, 0, stream>>>(
      zAH, zAL, wHp, wLp, lin0_b, nullptr, nullptr, hbP, nullptr, N, MTm);

  for (int l = 0; l < L; ++l) {
    gather_slice_kernel<<<dim3(HQ / 64, (N + 3) / 4), 256, 0, stream>>>(
        hbP, zAH, zAL, row_start, csr, N);
    gemm3_kernel<1, 0, 0><<<ggrid, 256, 0, stream>>>(
        zAH, zAL, wHp + (size_t)(1 + l) * HQ * HQ, wLp + (size_t)(1 + l) * HQ * HQ,
        b1 + (size_t)l * HQ, zBH, zBL, nullptr, nullptr, N, MTm);
    gemm3_kernel<1, 1, 0><<<ggrid, 256, 0, stream>>>(
        zBH, zBL, wHp + (size_t)(1 + L + l) * HQ * HQ, wLp + (size_t)(1 + L + l) * HQ * HQ,
        b2 + (size_t)l * HQ, zAH, zAL, nullptr, bnsums + 2 * HQ * l, N, MTm);
    bn_apply_tanh_kernel<<<dim3(HQ / 64, (N + 31) / 32), 256, 0, stream>>>(
        zAH, zAL, bnsums + 2 * HQ * l, gamma + (size_t)l * HQ, beta + (size_t)l * HQ,
        out + (size_t)(l + 1) * NH, hbP, N);
  }
}